// Round 18
// baseline (812.737 us; speedup 1.0000x reference)
//
#include <hip/hip_runtime.h>

// Problem constants: B=64, T=256, V=4096, H=512
// Inputs: x[B*T] i32, Wxh[V,H] f32, Whh[H,H] f32, bh[H] f32, Wo[H,V] f32, Bo[V] f32
// Output: out[B,T,V] f32 = (scan hs) @ Wo + Bo

typedef __fp16 half2_t __attribute__((ext_vector_type(2)));
typedef __attribute__((ext_vector_type(8))) short short8;   // 8 bf16 (MFMA A/B frag)
typedef __attribute__((ext_vector_type(4))) float f32x4;    // MFMA C/D frag

__device__ __forceinline__ unsigned short f32_to_bf16(float f) {
  unsigned int u = __builtin_bit_cast(unsigned int, f);
  u = (u + 0x7FFFu + ((u >> 16) & 1u)) >> 16;  // RNE
  return (unsigned short)u;
}

__device__ __forceinline__ unsigned int pack_f16x2(float a, float b) {
  half2_t h = __builtin_amdgcn_cvt_pkrtz(a, b);
  return __builtin_bit_cast(unsigned int, h);
}

__device__ __forceinline__ float fdot2_(unsigned int w, unsigned int h, float acc) {
  return __builtin_amdgcn_fdot2(__builtin_bit_cast(half2_t, w),
                                __builtin_bit_cast(half2_t, h), acc, false);
}

__device__ __forceinline__ void glds16(const void* g, void* lds) {
  __builtin_amdgcn_global_load_lds(
      (const __attribute__((address_space(1))) unsigned int*)g,
      (__attribute__((address_space(3))) unsigned int*)lds, 16, 0, 0);
}

// f32 -> f16 (RNE) -> e5m2 top-byte (RNE). Weights tiny: no overflow/inf.
__device__ __forceinline__ unsigned int q8_e5m2(float f) {
  _Float16 hv = (_Float16)f;
  unsigned short u = __builtin_bit_cast(unsigned short, hv);
  return (unsigned int)(((unsigned int)u + 0x7Fu + ((u >> 8) & 1u)) >> 8) & 0xFFu;
}

// ---------------------------------------------------------------------------
// Prep 1: Whh -> WhhE, e5m2 bytes, per-half-slice LDS image (256 KB total).
// u32 flat idx F = G*4 + d, G = ((s*2 + q2)*16 + u)*256 + c:
//   covers k-pairs m0 = q2*128 + u*8 + 2d, m0+1 of column j = s*256 + c.
//   bytes [b0,b1,b2,b3] = W[2m0], W[2m0+2], W[2m0+1], W[2m0+3] so that in
//   the scan lo=(w<<8)&0xFF00FF00 = f16 pair (W[2m0],W[2m0+1]) and
//   hi=w&0xFF00FF00 = f16 pair (W[2m0+2],W[2m0+3])  [R12-proven scheme].
// Also zeroes hG64 tags every launch (graph replays rerun this kernel).
// ---------------------------------------------------------------------------
__global__ __launch_bounds__(256) void pack_whhE(const float* __restrict__ Whh,
                                                 unsigned int* __restrict__ WhhE,
                                                 unsigned long long* __restrict__ hG64) {
  int idx = blockIdx.x * 256 + threadIdx.x;  // 65536 u32 total
  int d = idx & 3;
  int G = idx >> 2;
  int c = G & 255;
  int u = (G >> 8) & 15;
  int q2 = (G >> 12) & 1;
  int s = G >> 13;
  int m0 = q2 * 128 + u * 8 + 2 * d;   // first k-pair of this u32
  int j = s * 256 + c;                 // column
  unsigned int b0 = q8_e5m2(Whh[(2 * m0 + 0) * 512 + j]);
  unsigned int b2 = q8_e5m2(Whh[(2 * m0 + 1) * 512 + j]);
  unsigned int b1 = q8_e5m2(Whh[(2 * m0 + 2) * 512 + j]);
  unsigned int b3 = q8_e5m2(Whh[(2 * m0 + 3) * 512 + j]);
  WhhE[idx] = b0 | (b1 << 8) | (b2 << 16) | (b3 << 24);
  if (idx < 32768) hG64[idx] = 0ull;  // tag 0 != any target t>=1
}

// ---------------------------------------------------------------------------
// Prep 2: Wo [h][v] f32 -> WoT [v][h] bf16
// ---------------------------------------------------------------------------
__global__ __launch_bounds__(256) void transpose_wo(const float* __restrict__ Wo,
                                                    unsigned short* __restrict__ WoT) {
  __shared__ float tile[64][65];
  const int tv = blockIdx.x;   // 0..63  (V/64)
  const int th = blockIdx.y;   // 0..7   (H/64)
  const int tid = threadIdx.x;
  const int c = tid & 63, r4 = tid >> 6;
#pragma unroll
  for (int p = 0; p < 16; ++p) {
    int hl = p * 4 + r4;
    tile[hl][c] = Wo[(size_t)(th * 64 + hl) * 4096 + tv * 64 + c];
  }
  __syncthreads();
#pragma unroll
  for (int p = 0; p < 16; ++p) {
    int vl = p * 4 + r4;
    WoT[(size_t)(tv * 64 + vl) * 512 + th * 64 + c] = f32_to_bf16(tile[c][vl]);
  }
}

// ---------------------------------------------------------------------------
// Recurrence vE: 2-WAY SPLIT, all-e5m2 LDS weights. 128 blocks = 64 batches
// x 2 half-slices; block (b,s) owns cols [256s,256s+256) = 128 KB e5m2 in
// LDS (R12-proven byte-mask unpack feeds fdot2 directly). Benefits vs R17:
// (a) waves with q2==s dot against LOCALLY-produced h -> 50% of compute
// overlaps the store->visibility window (was 25%); (b) 2 sync parties and
// 128 tagged words (was 4 parties / 192+128) -> less LLC spin contention.
// Sync protocol: UNCHANGED R15 tagged-u64 agent-scope relaxed atomics,
// parity double-buffer, tags zeroed per launch (WAR proof carries over).
// Thread (c=tid&255, q2=tid>>8): col j=256s+c, k-half q2 (16 e5m2 uint4
// chunks). 1 block/CU (133 KB LDS), 128 co-resident by capacity.
// Precision: all-e5m2 Whh -> predicted absmax ~1.8e-4 (thr 2.6e-4; R12
// measured 1.53e-4 at 75% e5m2). Fallback if fail: R17 f16 4-way.
// ---------------------------------------------------------------------------
#define DOTCH(u_) do { \
  const uint4 w_ = wl[(q2 * 16 + (u_)) * 256 + c]; \
  const uint4 hA = hbuf[q2 * 32 + 2 * (u_)]; \
  const uint4 hB = hbuf[q2 * 32 + 2 * (u_) + 1]; \
  unsigned int lo_, hi_; \
  lo_ = (w_.x << 8) & 0xFF00FF00u; hi_ = w_.x & 0xFF00FF00u; \
  a0 = fdot2_(lo_, hA.x, a0); a1 = fdot2_(hi_, hA.y, a1); \
  lo_ = (w_.y << 8) & 0xFF00FF00u; hi_ = w_.y & 0xFF00FF00u; \
  a2 = fdot2_(lo_, hA.z, a2); a3 = fdot2_(hi_, hA.w, a3); \
  lo_ = (w_.z << 8) & 0xFF00FF00u; hi_ = w_.z & 0xFF00FF00u; \
  a0 = fdot2_(lo_, hB.x, a0); a1 = fdot2_(hi_, hB.y, a1); \
  lo_ = (w_.w << 8) & 0xFF00FF00u; hi_ = w_.w & 0xFF00FF00u; \
  a2 = fdot2_(lo_, hB.z, a2); a3 = fdot2_(hi_, hB.w, a3); } while (0)

#define DOTALL() do { \
  DOTCH(0);  DOTCH(1);  DOTCH(2);  DOTCH(3); \
  DOTCH(4);  DOTCH(5);  DOTCH(6);  DOTCH(7); \
  DOTCH(8);  DOTCH(9);  DOTCH(10); DOTCH(11); \
  DOTCH(12); DOTCH(13); DOTCH(14); DOTCH(15); } while (0)

__global__ __launch_bounds__(512) void rnn_scanE(const int* __restrict__ x,
                                                 const float* __restrict__ Wxh,
                                                 const unsigned int* __restrict__ WhhE,
                                                 const float* __restrict__ bh,
                                                 unsigned short* __restrict__ hs,
                                                 unsigned long long* hG64) {
  __shared__ uint4 wl[8192];     // 128 KB: this block's 256-col e5m2 slice
  __shared__ uint4 hbuf[64];     // 512 h values as f16 pairs
  __shared__ float pbuf[512];    // partials [q2][c]
  __shared__ int toks[256];
  const int bid = blockIdx.x;
  const int s = bid & 1;         // half-slice
  const int b = bid >> 1;        // batch
  const int tid = threadIdx.x;
  const int c = tid & 255;
  const int q2 = tid >> 8;       // k-half (wave-uniform: 4 waves each)
  const uint4* W4E = (const uint4*)WhhE;

  // stage this block's 128 KB e5m2 slice (coalesced, 16 rounds)
#pragma unroll
  for (int it = 0; it < 16; ++it) {
    int L = it * 512 + tid;
    wl[L] = W4E[s * 8192 + L];
  }
  if (tid < 64) hbuf[tid] = make_uint4(0u, 0u, 0u, 0u);  // h0 = 0
  if (tid < 256) toks[tid] = x[b * 256 + tid];
  __syncthreads();

  unsigned int* hb32 = (unsigned int*)hbuf;      // [256] u32 view of h pairs
  const float bhj = (tid < 256) ? bh[s * 256 + tid] : 0.f;

  for (int t = 0; t < 256; ++t) {
    const int tok = toks[t];
    // xv prefetch (finalize threads), resolved well before use
    const float xv = (tid < 256) ? Wxh[(size_t)tok * 512 + s * 256 + tid] : 0.f;

    float a0 = 0.f, a1 = 0.f, a2 = 0.f, a3 = 0.f;
    if (q2 == s) {
      // phase 1: local-h waves compute during siblings' store->visibility
      DOTALL();
    } else if (t > 0 && (tid & 255) < 128) {
      // pollers: pull 128 remote u-pairs, tanh on receipt
      const int r = 128 * (1 - s) + (tid & 127);
      const unsigned long long* src =
          hG64 + (((size_t)(t & 1)) << 14) + b * 256 + r;
      unsigned long long v;
      do {
        v = __hip_atomic_load(src, __ATOMIC_RELAXED, __HIP_MEMORY_SCOPE_AGENT);
      } while ((unsigned)(v >> 32) != (unsigned)t);
      half2_t up = __builtin_bit_cast(half2_t, (unsigned)v);
      hb32[r] = pack_f16x2(tanhf((float)up.x), tanhf((float)up.y));
    }
    __syncthreads();  // remote half of hbuf ready

    if (q2 != s) DOTALL();  // phase 2: remote-h waves
    pbuf[q2 * 256 + c] = (a0 + a1) + (a2 + a3);
    __syncthreads();

    // finalize: 256 threads x 1 col; store tagged pre-tanh u FIRST
    if (tid < 256) {
      const float ssum = pbuf[tid] + pbuf[256 + tid];
      const float u1 = xv + ssum + bhj;
      const float u2 = __shfl_down(u1, 1);  // odd partner's u
      if (!(tid & 1)) {
        const unsigned int up = pack_f16x2(u1, u2);
        __hip_atomic_store(
            hG64 + (((size_t)((t + 1) & 1)) << 14) + b * 256 + 128 * s + (tid >> 1),
            ((unsigned long long)(unsigned)(t + 1) << 32) | up,
            __ATOMIC_RELAXED, __HIP_MEMORY_SCOPE_AGENT);
        // own h from the SAME rounded u (bit-consistent with the sibling)
        half2_t uo = __builtin_bit_cast(half2_t, up);
        const float h1 = tanhf((float)uo.x);
        const float h2 = tanhf((float)uo.y);
        hb32[128 * s + (tid >> 1)] = pack_f16x2(h1, h2);
        ((unsigned int*)hs)[(size_t)(b * 256 + t) * 256 + 128 * s + (tid >> 1)] =
            (unsigned int)f32_to_bf16(h1) | ((unsigned int)f32_to_bf16(h2) << 16);
      }
    }
    __syncthreads();  // own-slice LDS update visible; pbuf reusable
  }
}

// ---------------------------------------------------------------------------
// Output GEMM: C[16384,4096] = A[16384,512](bf16) @ WoT^T + Bo.  m97 structure.
// ---------------------------------------------------------------------------
__global__ __launch_bounds__(256) void gemm_out(const unsigned short* __restrict__ A,
                                                const unsigned short* __restrict__ Bt,
                                                const float* __restrict__ Bo,
                                                float* __restrict__ C) {
  __shared__ alignas(16) unsigned short As[128 * 32];
  __shared__ alignas(16) unsigned short Bs[128 * 32];
  const int tid = threadIdx.x;
  const int lane = tid & 63, wid = tid >> 6;
  const int bn = blockIdx.x & 31, bm = blockIdx.x >> 5;
  const int wr = wid >> 1, wc = wid & 1;

  f32x4 acc[4][4] = {};

  const unsigned short* Ag = A + (size_t)(bm * 128 + (tid >> 2)) * 512 + (tid & 3) * 8;
  const unsigned short* Bg = Bt + (size_t)(bn * 128 + (tid >> 2)) * 512 + (tid & 3) * 8;
  char* AsW = (char*)As + wid * 1024;
  char* BsW = (char*)Bs + wid * 1024;

  const int laneRow = lane & 15;
  const int k0 = (lane >> 4) * 8;

  for (int kt = 0; kt < 16; ++kt) {
    __syncthreads();
    const unsigned short* a0 = Ag + kt * 32;
    const unsigned short* b0 = Bg + kt * 32;
    glds16(a0,            AsW);
    glds16(a0 + 64 * 512, AsW + 4096);
    glds16(b0,            BsW);
    glds16(b0 + 64 * 512, BsW + 4096);
    __syncthreads();

    short8 af[4], bf[4];
#pragma unroll
    for (int f = 0; f < 4; ++f)
      af[f] = *(const short8*)&As[(wr * 64 + f * 16 + laneRow) * 32 + k0];
#pragma unroll
    for (int f = 0; f < 4; ++f)
      bf[f] = *(const short8*)&Bs[(wc * 64 + f * 16 + laneRow) * 32 + k0];
#pragma unroll
    for (int fm = 0; fm < 4; ++fm)
#pragma unroll
      for (int fn = 0; fn < 4; ++fn)
        acc[fm][fn] = __builtin_amdgcn_mfma_f32_16x16x32_bf16(af[fm], bf[fn], acc[fm][fn], 0, 0, 0);
  }

  const int mg0 = bm * 128 + wr * 64, ng0 = bn * 128 + wc * 64;
#pragma unroll
  for (int fn = 0; fn < 4; ++fn) {
    const int col = ng0 + fn * 16 + laneRow;
    const float bo = Bo[col];
#pragma unroll
    for (int fm = 0; fm < 4; ++fm) {
      const int row0 = mg0 + fm * 16 + (lane >> 4) * 4;
#pragma unroll
      for (int r = 0; r < 4; ++r)
        C[(size_t)(row0 + r) * 4096 + col] = acc[fm][fn][r] + bo;
    }
  }
}

// ---------------------------------------------------------------------------
extern "C" void kernel_launch(void* const* d_in, const int* in_sizes, int n_in,
                              void* d_out, int out_size, void* d_ws, size_t ws_size,
                              hipStream_t stream) {
  (void)in_sizes; (void)n_in; (void)out_size; (void)ws_size;
  const int* x = (const int*)d_in[0];
  const float* Wxh = (const float*)d_in[1];
  const float* Whh = (const float*)d_in[2];
  const float* bh = (const float*)d_in[3];
  const float* Wo = (const float*)d_in[4];
  const float* Bo = (const float*)d_in[5];
  float* out = (float*)d_out;

  // workspace map (bytes):
  //   WhhE   @ 0         256 KB
  //   WoT    @ 262144    4 MB
  //   hs     @ 4456448   16 MB
  //   hG64   @ 21233664  256 KB   (2 x 64 x 256 tagged u64)
  unsigned int* WhhE = (unsigned int*)d_ws;
  unsigned short* WoT = (unsigned short*)((char*)d_ws + 262144);
  unsigned short* hs = (unsigned short*)((char*)d_ws + 4456448);
  unsigned long long* hG64 = (unsigned long long*)((char*)d_ws + 21233664);

  hipLaunchKernelGGL(pack_whhE, dim3(256), dim3(256), 0, stream, Whh, WhhE, hG64);
  hipLaunchKernelGGL(transpose_wo, dim3(64, 8), dim3(256), 0, stream, Wo, WoT);
  hipLaunchKernelGGL(rnn_scanE, dim3(128), dim3(512), 0, stream, x, Wxh, WhhE, bh,
                     hs, hG64);
  hipLaunchKernelGGL(gemm_out, dim3(4096), dim3(256), 0, stream, hs, WoT, Bo, out);
}

// Round 19
// 582.135 us; speedup vs baseline: 1.3961x; 1.3961x over previous
//
#include <hip/hip_runtime.h>

// Problem constants: B=64, T=256, V=4096, H=512
// Inputs: x[B*T] i32, Wxh[V,H] f32, Whh[H,H] f32, bh[H] f32, Wo[H,V] f32, Bo[V] f32
// Output: out[B,T,V] f32 = (scan hs) @ Wo + Bo

typedef __fp16 half2_t __attribute__((ext_vector_type(2)));
typedef __attribute__((ext_vector_type(8))) short short8;   // 8 bf16 (MFMA A/B frag)
typedef __attribute__((ext_vector_type(4))) float f32x4;    // MFMA C/D frag

__device__ __forceinline__ unsigned short f32_to_bf16(float f) {
  unsigned int u = __builtin_bit_cast(unsigned int, f);
  u = (u + 0x7FFFu + ((u >> 16) & 1u)) >> 16;  // RNE
  return (unsigned short)u;
}

__device__ __forceinline__ unsigned int pack_f16x2(float a, float b) {
  half2_t h = __builtin_amdgcn_cvt_pkrtz(a, b);
  return __builtin_bit_cast(unsigned int, h);
}

__device__ __forceinline__ float fdot2_(unsigned int w, unsigned int h, float acc) {
  return __builtin_amdgcn_fdot2(__builtin_bit_cast(half2_t, w),
                                __builtin_bit_cast(half2_t, h), acc, false);
}

__device__ __forceinline__ void glds16(const void* g, void* lds) {
  __builtin_amdgcn_global_load_lds(
      (const __attribute__((address_space(1))) unsigned int*)g,
      (__attribute__((address_space(3))) unsigned int*)lds, 16, 0, 0);
}

// f32 -> f16 (RNE) -> e5m2 top-byte (RNE). Weights tiny: no overflow/inf.
__device__ __forceinline__ unsigned int q8_e5m2(float f) {
  _Float16 hv = (_Float16)f;
  unsigned short u = __builtin_bit_cast(unsigned short, hv);
  return (unsigned int)(((unsigned int)u + 0x7Fu + ((u >> 8) & 1u)) >> 8) & 0xFFu;
}

// ---------------------------------------------------------------------------
// Prep 1: Whh -> WhhE2, e5m2 bytes, 4-way per-slice LDS image (256 KB total).
// uint4 index G = (s*32 + kappa)*128 + c  (s=slice, kappa=0..31 chunk, c=col
// within slice); u32 d of chunk kappa covers h-pairs m0 = 8*kappa + 2d and
// m0+1 of column j = s*128 + c, bytes [b0,b1,b2,b3] = W[2m0], W[2m0+2],
// W[2m0+1], W[2m0+3] so in-scan lo=(w<<8)&0xFF00FF00 = f16 pair
// (W[2m0],W[2m0+1]) and hi=w&0xFF00FF00 = pair (W[2m0+2],W[2m0+3])
// [R12/R18-proven scheme]. Also zeroes hG64 tags every launch.
// ---------------------------------------------------------------------------
__global__ __launch_bounds__(256) void pack_whhE2(const float* __restrict__ Whh,
                                                  unsigned int* __restrict__ WhhE2,
                                                  unsigned long long* __restrict__ hG64) {
  int idx = blockIdx.x * 256 + threadIdx.x;  // 65536 u32 total
  int d = idx & 3;
  int G = idx >> 2;
  int c = G & 127;
  int kappa = (G >> 7) & 31;
  int s = G >> 12;
  int m0 = 8 * kappa + 2 * d;   // first h-pair of this u32
  int j = s * 128 + c;          // column
  unsigned int b0 = q8_e5m2(Whh[(2 * m0 + 0) * 512 + j]);
  unsigned int b2 = q8_e5m2(Whh[(2 * m0 + 1) * 512 + j]);
  unsigned int b1 = q8_e5m2(Whh[(2 * m0 + 2) * 512 + j]);
  unsigned int b3 = q8_e5m2(Whh[(2 * m0 + 3) * 512 + j]);
  WhhE2[idx] = b0 | (b1 << 8) | (b2 << 16) | (b3 << 24);
  if (idx < 32768) hG64[idx] = 0ull;  // tag 0 != any target t>=1
}

// ---------------------------------------------------------------------------
// Prep 2: Wo [h][v] f32 -> WoT [v][h] bf16
// ---------------------------------------------------------------------------
__global__ __launch_bounds__(256) void transpose_wo(const float* __restrict__ Wo,
                                                    unsigned short* __restrict__ WoT) {
  __shared__ float tile[64][65];
  const int tv = blockIdx.x;   // 0..63  (V/64)
  const int th = blockIdx.y;   // 0..7   (H/64)
  const int tid = threadIdx.x;
  const int c = tid & 63, r4 = tid >> 6;
#pragma unroll
  for (int p = 0; p < 16; ++p) {
    int hl = p * 4 + r4;
    tile[hl][c] = Wo[(size_t)(th * 64 + hl) * 4096 + tv * 64 + c];
  }
  __syncthreads();
#pragma unroll
  for (int p = 0; p < 16; ++p) {
    int vl = p * 4 + r4;
    WoT[(size_t)(tv * 64 + vl) * 512 + th * 64 + c] = f32_to_bf16(tile[c][vl]);
  }
}

// ---------------------------------------------------------------------------
// Recurrence vF: EXACT R17 structure (4 blocks/batch, proven 424us sync
// protocol and phase interleave) with ONE change: LDS weights are e5m2
// (64 KB/block, was 128 KB f16) -> weight LDS traffic halves. R18 lesson:
// do NOT change the split (concentrating work lengthens the chain); R18's
// one useful datum: all-e5m2 Whh passes precision (measured 1.68e-4 < 2.6e-4).
// Thread (c=tid&127, q=tid>>7): col j=128s+c; its 8 e5m2 chunks span ALL
// FOUR quarters (2 per quarter: kappa = 8Q + 2q + {0,1}) so the own-quarter
// 25% pre-poll overlap survives. Unpack = R12-proven byte masks.
// ---------------------------------------------------------------------------
#define DOTCH(k_) do { \
  const uint4 w_ = wl[(k_) * 128 + c]; \
  const uint4 hA = hbuf[2 * (k_)]; \
  const uint4 hB = hbuf[2 * (k_) + 1]; \
  unsigned int lo_, hi_; \
  lo_ = (w_.x << 8) & 0xFF00FF00u; hi_ = w_.x & 0xFF00FF00u; \
  a0 = fdot2_(lo_, hA.x, a0); a1 = fdot2_(hi_, hA.y, a1); \
  lo_ = (w_.y << 8) & 0xFF00FF00u; hi_ = w_.y & 0xFF00FF00u; \
  a2 = fdot2_(lo_, hA.z, a2); a3 = fdot2_(hi_, hA.w, a3); \
  lo_ = (w_.z << 8) & 0xFF00FF00u; hi_ = w_.z & 0xFF00FF00u; \
  a0 = fdot2_(lo_, hB.x, a0); a1 = fdot2_(hi_, hB.y, a1); \
  lo_ = (w_.w << 8) & 0xFF00FF00u; hi_ = w_.w & 0xFF00FF00u; \
  a2 = fdot2_(lo_, hB.z, a2); a3 = fdot2_(hi_, hB.w, a3); } while (0)

__global__ __launch_bounds__(512) void rnn_scanF(const int* __restrict__ x,
                                                 const float* __restrict__ Wxh,
                                                 const unsigned int* __restrict__ WhhE2,
                                                 const float* __restrict__ bh,
                                                 unsigned short* __restrict__ hs,
                                                 unsigned long long* hG64) {
  __shared__ uint4 wl[4096];     // 64 KB: this block's 128-col e5m2 slice
  __shared__ uint4 hbuf[64];     // 512 h values as f16 pairs
  __shared__ float pbuf[512];    // partials [q][c]
  __shared__ int toks[256];
  const int bid = blockIdx.x;
  const int s = bid & 3;         // column-slice (R15/R17 mapping, proven)
  const int b = bid >> 2;        // batch
  const int tid = threadIdx.x;
  const int c = tid & 127;
  const int q = tid >> 7;        // k-phase (wave-pair uniform)
  const uint4* W4E = (const uint4*)WhhE2;

  // stage this block's 64 KB e5m2 slice (coalesced, 8 rounds)
#pragma unroll
  for (int it = 0; it < 8; ++it) {
    int L = it * 512 + tid;
    wl[L] = W4E[s * 4096 + L];
  }
  if (tid < 64) hbuf[tid] = make_uint4(0u, 0u, 0u, 0u);  // h0 = 0
  if (tid < 256) toks[tid] = x[b * 256 + tid];
  __syncthreads();

  unsigned int* hb32 = (unsigned int*)hbuf;      // [256] u32 view of h pairs
  const float bhj = (tid < 128) ? bh[s * 128 + tid] : 0.f;

  for (int t = 0; t < 256; ++t) {
    const int tok = toks[t];
    // xv prefetch at loop top; resolved long before finalize uses it
    const float xv = (tid < 128) ? Wxh[(size_t)tok * 512 + s * 128 + tid] : 0.f;

    float a0 = 0.f, a1 = 0.f, a2 = 0.f, a3 = 0.f;
    // phase 1: own-quarter chunks (h from local write last step) --
    // overlaps the siblings' store->LLC-visibility window
    DOTCH(8 * s + 2 * q);
    DOTCH(8 * s + 2 * q + 1);

    if (t > 0 && tid < 192) {
      // pull 192 remote u-pairs: spin on own tagged word, tanh on receipt
      const int r = (tid < s * 64) ? tid : tid + 64;  // skip own slice
      const unsigned long long* src =
          hG64 + (((size_t)(t & 1)) << 14) + b * 256 + r;
      unsigned long long v;
      do {
        v = __hip_atomic_load(src, __ATOMIC_RELAXED, __HIP_MEMORY_SCOPE_AGENT);
      } while ((unsigned)(v >> 32) != (unsigned)t);
      half2_t up = __builtin_bit_cast(half2_t, (unsigned)v);
      hb32[r] = pack_f16x2(tanhf((float)up.x), tanhf((float)up.y));
    }
    __syncthreads();

    // phase 2: the three remote quarters (2 chunks each)
    {
      const int m1 = ((s + 1) & 3) * 8 + 2 * q;
      DOTCH(m1); DOTCH(m1 + 1);
      const int m2 = ((s + 2) & 3) * 8 + 2 * q;
      DOTCH(m2); DOTCH(m2 + 1);
      const int m3 = ((s + 3) & 3) * 8 + 2 * q;
      DOTCH(m3); DOTCH(m3 + 1);
    }
    pbuf[q * 128 + c] = (a0 + a1) + (a2 + a3);
    __syncthreads();

    // finalize: 128 threads x 1 col; store tagged pre-tanh u FIRST
    if (tid < 128) {
      const float ssum = pbuf[tid] + pbuf[tid + 128] + pbuf[tid + 256] + pbuf[tid + 384];
      const float u1 = xv + ssum + bhj;
      const float u2 = __shfl_down(u1, 1);  // odd partner's u (pair in-wave)
      if (!(tid & 1)) {
        const unsigned int up = pack_f16x2(u1, u2);
        __hip_atomic_store(
            hG64 + (((size_t)((t + 1) & 1)) << 14) + b * 256 + 64 * s + (tid >> 1),
            ((unsigned long long)(unsigned)(t + 1) << 32) | up,
            __ATOMIC_RELAXED, __HIP_MEMORY_SCOPE_AGENT);
        // own h from the SAME rounded u (bit-consistent with readers)
        half2_t uo = __builtin_bit_cast(half2_t, up);
        const float h1 = tanhf((float)uo.x);
        const float h2 = tanhf((float)uo.y);
        hb32[64 * s + (tid >> 1)] = pack_f16x2(h1, h2);
        ((unsigned int*)hs)[(size_t)(b * 256 + t) * 256 + 64 * s + (tid >> 1)] =
            (unsigned int)f32_to_bf16(h1) | ((unsigned int)f32_to_bf16(h2) << 16);
      }
    }
    __syncthreads();  // own-slice LDS update visible; pbuf reusable
  }
}

// ---------------------------------------------------------------------------
// Output GEMM: C[16384,4096] = A[16384,512](bf16) @ WoT^T + Bo.  m97 structure.
// ---------------------------------------------------------------------------
__global__ __launch_bounds__(256) void gemm_out(const unsigned short* __restrict__ A,
                                                const unsigned short* __restrict__ Bt,
                                                const float* __restrict__ Bo,
                                                float* __restrict__ C) {
  __shared__ alignas(16) unsigned short As[128 * 32];
  __shared__ alignas(16) unsigned short Bs[128 * 32];
  const int tid = threadIdx.x;
  const int lane = tid & 63, wid = tid >> 6;
  const int bn = blockIdx.x & 31, bm = blockIdx.x >> 5;
  const int wr = wid >> 1, wc = wid & 1;

  f32x4 acc[4][4] = {};

  const unsigned short* Ag = A + (size_t)(bm * 128 + (tid >> 2)) * 512 + (tid & 3) * 8;
  const unsigned short* Bg = Bt + (size_t)(bn * 128 + (tid >> 2)) * 512 + (tid & 3) * 8;
  char* AsW = (char*)As + wid * 1024;
  char* BsW = (char*)Bs + wid * 1024;

  const int laneRow = lane & 15;
  const int k0 = (lane >> 4) * 8;

  for (int kt = 0; kt < 16; ++kt) {
    __syncthreads();
    const unsigned short* a0 = Ag + kt * 32;
    const unsigned short* b0 = Bg + kt * 32;
    glds16(a0,            AsW);
    glds16(a0 + 64 * 512, AsW + 4096);
    glds16(b0,            BsW);
    glds16(b0 + 64 * 512, BsW + 4096);
    __syncthreads();

    short8 af[4], bf[4];
#pragma unroll
    for (int f = 0; f < 4; ++f)
      af[f] = *(const short8*)&As[(wr * 64 + f * 16 + laneRow) * 32 + k0];
#pragma unroll
    for (int f = 0; f < 4; ++f)
      bf[f] = *(const short8*)&Bs[(wc * 64 + f * 16 + laneRow) * 32 + k0];
#pragma unroll
    for (int fm = 0; fm < 4; ++fm)
#pragma unroll
      for (int fn = 0; fn < 4; ++fn)
        acc[fm][fn] = __builtin_amdgcn_mfma_f32_16x16x32_bf16(af[fm], bf[fn], acc[fm][fn], 0, 0, 0);
  }

  const int mg0 = bm * 128 + wr * 64, ng0 = bn * 128 + wc * 64;
#pragma unroll
  for (int fn = 0; fn < 4; ++fn) {
    const int col = ng0 + fn * 16 + laneRow;
    const float bo = Bo[col];
#pragma unroll
    for (int fm = 0; fm < 4; ++fm) {
      const int row0 = mg0 + fm * 16 + (lane >> 4) * 4;
#pragma unroll
      for (int r = 0; r < 4; ++r)
        C[(size_t)(row0 + r) * 4096 + col] = acc[fm][fn][r] + bo;
    }
  }
}

// ---------------------------------------------------------------------------
extern "C" void kernel_launch(void* const* d_in, const int* in_sizes, int n_in,
                              void* d_out, int out_size, void* d_ws, size_t ws_size,
                              hipStream_t stream) {
  (void)in_sizes; (void)n_in; (void)out_size; (void)ws_size;
  const int* x = (const int*)d_in[0];
  const float* Wxh = (const float*)d_in[1];
  const float* Whh = (const float*)d_in[2];
  const float* bh = (const float*)d_in[3];
  const float* Wo = (const float*)d_in[4];
  const float* Bo = (const float*)d_in[5];
  float* out = (float*)d_out;

  // workspace map (bytes):
  //   WhhE2  @ 0         256 KB
  //   WoT    @ 262144    4 MB
  //   hs     @ 4456448   16 MB
  //   hG64   @ 21233664  256 KB   (2 x 64 x 256 tagged u64)
  unsigned int* WhhE2 = (unsigned int*)d_ws;
  unsigned short* WoT = (unsigned short*)((char*)d_ws + 262144);
  unsigned short* hs = (unsigned short*)((char*)d_ws + 4456448);
  unsigned long long* hG64 = (unsigned long long*)((char*)d_ws + 21233664);

  hipLaunchKernelGGL(pack_whhE2, dim3(256), dim3(256), 0, stream, Whh, WhhE2, hG64);
  hipLaunchKernelGGL(transpose_wo, dim3(64, 8), dim3(256), 0, stream, Wo, WoT);
  hipLaunchKernelGGL(rnn_scanF, dim3(256), dim3(512), 0, stream, x, Wxh, WhhE2, bh,
                     hs, hG64);
  hipLaunchKernelGGL(gemm_out, dim3(4096), dim3(256), 0, stream, hs, WoT, Bo, out);
}